// Round 2
// baseline (188.245 us; speedup 1.0000x reference)
//
#include <hip/hip_runtime.h>

// SparseDopplerAttention on gfx950 — R2.
// 1 block = 1 range (256 blocks, 1/CU, LDS-capped). 512 threads = 8 waves.
// Phase A (barrier-free): each wave loads its 64 x-rows as MFMA fragments
// directly from global, projects K^T/V/Q^T (operand-swap for K,Q gives b64
// LDS writes), Q transposed to B-frags via per-wave scratch. One barrier.
// Phase B: flash attention in S^T orientation, no-max softmax (exp2 safe),
// deferred l-reduction, prefetched K frags, pure MFMA PV chain.

#define NK 512
#define DOP 64
#define FIN 96

typedef __bf16 bf16;
typedef bf16 v4bf __attribute__((ext_vector_type(4)));
typedef bf16 v8bf __attribute__((ext_vector_type(8)));
typedef float v4f __attribute__((ext_vector_type(4)));

__device__ __forceinline__ v8bf pk8(float4 a, float4 b) {
    v8bf r;
    r[0] = (bf16)a.x; r[1] = (bf16)a.y; r[2] = (bf16)a.z; r[3] = (bf16)a.w;
    r[4] = (bf16)b.x; r[5] = (bf16)b.y; r[6] = (bf16)b.z; r[7] = (bf16)b.w;
    return r;
}

__global__ __launch_bounds__(512, 2)
void sda_kernel(const float* __restrict__ power,
                const int*   __restrict__ ele_i,
                const int*   __restrict__ azi_i,
                const float* __restrict__ ele_t,
                const float* __restrict__ azi_t,
                const float* __restrict__ Wq, const float* __restrict__ bq,
                const float* __restrict__ Wk, const float* __restrict__ bk,
                const float* __restrict__ Wv, const float* __restrict__ bv,
                float* __restrict__ out)
{
    extern __shared__ char smem[];
    char* Kb = smem;            // 64 KB: K [key][dim] bf16, 128 B rows, blk16 ^= key&7
    char* Vt = smem + 65536;    // 64 KB: V^T [dim][key] bf16, 1024 B rows, blk16 ^= dim&7

    const int tid  = threadIdx.x;
    const int wave = tid >> 6;
    const int lane = tid & 63;
    const int l15  = lane & 15;
    const int quad = lane >> 4;
    const int range = blockIdx.x;
    const int rowbase = range * NK + wave * 64;   // this wave's rows/queries/keys

    char* Sw = smem + 131072 + wave * 4096;       // per-wave scratch (Q transpose, then P^T)

    // ---------------- x fragments straight from global ----------------
    // xa[mt][kt]: A-frag of x rows (rowbase + mt*16 + l15), feats kt*32+quad*8..+7
    v8bf xa[4][3];
#pragma unroll
    for (int mt = 0; mt < 4; mt++) {
        int row = rowbase + mt * 16 + l15;
        const float* pr = power + (size_t)row * DOP;
        xa[mt][0] = pk8(*(const float4*)(pr + quad * 8), *(const float4*)(pr + quad * 8 + 4));
        xa[mt][1] = pk8(*(const float4*)(pr + 32 + quad * 8), *(const float4*)(pr + 32 + quad * 8 + 4));
        int ie = ele_i[row];
        int ia = azi_i[row];
        const float* tb = (quad < 2) ? (ele_t + ie * 16 + quad * 8)
                                     : (azi_t + ia * 16 + (quad - 2) * 8);
        xa[mt][2] = pk8(*(const float4*)tb, *(const float4*)(tb + 4));
    }

    // ---------------- K^T = Wk @ x^T  (b64 writes along dim) ----------------
    {
        v8bf wk[4][3];
#pragma unroll
        for (int t4 = 0; t4 < 4; t4++)
#pragma unroll
            for (int kt = 0; kt < 3; kt++) {
                const float* p = Wk + (t4 * 16 + l15) * FIN + kt * 32 + quad * 8;
                wk[t4][kt] = pk8(*(const float4*)p, *(const float4*)(p + 4));
            }
#pragma unroll
        for (int mtd = 0; mtd < 4; mtd++) {     // dim tile
            float4 bk4 = *(const float4*)(bk + mtd * 16 + quad * 4);
#pragma unroll
            for (int ntr = 0; ntr < 4; ntr++) { // key-row tile
                v4f acc = {0.f, 0.f, 0.f, 0.f};
#pragma unroll
                for (int kt = 0; kt < 3; kt++)
                    acc = __builtin_amdgcn_mfma_f32_16x16x32_bf16(wk[mtd][kt], xa[ntr][kt], acc, 0, 0, 0);
                int keyb = wave * 64 + ntr * 16 + l15;      // block-local key
                v4bf o;
                o[0] = (bf16)(acc[0] + bk4.x); o[1] = (bf16)(acc[1] + bk4.y);
                o[2] = (bf16)(acc[2] + bk4.z); o[3] = (bf16)(acc[3] + bk4.w);
                *(v4bf*)(Kb + keyb * 128 +
                         ((((mtd * 2 + (quad >> 1)) ^ (keyb & 7)) << 4) | ((quad & 1) << 3))) = o;
            }
        }
    }

    // ---------------- V = x @ Wv^T  (b64 writes along key into V^T) ----------------
    {
        v8bf wv[4][3];
#pragma unroll
        for (int t4 = 0; t4 < 4; t4++)
#pragma unroll
            for (int kt = 0; kt < 3; kt++) {
                const float* p = Wv + (t4 * 16 + l15) * FIN + kt * 32 + quad * 8;
                wv[t4][kt] = pk8(*(const float4*)p, *(const float4*)(p + 4));
            }
        float bv4[4];
#pragma unroll
        for (int nt = 0; nt < 4; nt++) bv4[nt] = bv[nt * 16 + l15];
#pragma unroll
        for (int mt = 0; mt < 4; mt++) {        // key-row tile
#pragma unroll
            for (int nt = 0; nt < 4; nt++) {    // dim tile
                v4f acc = {0.f, 0.f, 0.f, 0.f};
#pragma unroll
                for (int kt = 0; kt < 3; kt++)
                    acc = __builtin_amdgcn_mfma_f32_16x16x32_bf16(xa[mt][kt], wv[nt][kt], acc, 0, 0, 0);
                int dim  = nt * 16 + l15;
                int blk  = (wave * 8 + mt * 2 + (quad >> 1)) ^ (dim & 7);
                v4bf o;
                o[0] = (bf16)(acc[0] + bv4[nt]); o[1] = (bf16)(acc[1] + bv4[nt]);
                o[2] = (bf16)(acc[2] + bv4[nt]); o[3] = (bf16)(acc[3] + bv4[nt]);
                *(v4bf*)(Vt + dim * 1024 + ((blk << 4) | ((quad & 1) << 3))) = o;
            }
        }
    }

    // ---------------- Q^T = Wq @ x^T, fold 0.125*log2(e), transpose to B-frags ----------------
    v8bf qf[4][2];
    {
        v8bf wq[4][3];
#pragma unroll
        for (int t4 = 0; t4 < 4; t4++)
#pragma unroll
            for (int kt = 0; kt < 3; kt++) {
                const float* p = Wq + (t4 * 16 + l15) * FIN + kt * 32 + quad * 8;
                wq[t4][kt] = pk8(*(const float4*)p, *(const float4*)(p + 4));
            }
        float4 bq4[4];
#pragma unroll
        for (int mtd = 0; mtd < 4; mtd++) bq4[mtd] = *(const float4*)(bq + mtd * 16 + quad * 4);
#pragma unroll
        for (int pass = 0; pass < 2; pass++) {   // 32 queries per pass (4 KB scratch)
#pragma unroll
            for (int mtd = 0; mtd < 4; mtd++)
#pragma unroll
                for (int nn = 0; nn < 2; nn++) {
                    v4f acc = {0.f, 0.f, 0.f, 0.f};
#pragma unroll
                    for (int kt = 0; kt < 3; kt++)
                        acc = __builtin_amdgcn_mfma_f32_16x16x32_bf16(wq[mtd][kt], xa[pass * 2 + nn][kt], acc, 0, 0, 0);
                    int row = nn * 16 + l15;     // scratch row 0..31
                    v4bf o;
                    o[0] = (bf16)((acc[0] + bq4[mtd].x) * 0.18033688011112042f);
                    o[1] = (bf16)((acc[1] + bq4[mtd].y) * 0.18033688011112042f);
                    o[2] = (bf16)((acc[2] + bq4[mtd].z) * 0.18033688011112042f);
                    o[3] = (bf16)((acc[3] + bq4[mtd].w) * 0.18033688011112042f);
                    *(v4bf*)(Sw + row * 128 +
                             ((((mtd * 2 + (quad >> 1)) ^ (row & 7)) << 4) | ((quad & 1) << 3))) = o;
                }
#pragma unroll
            for (int nn = 0; nn < 2; nn++)
#pragma unroll
                for (int kt = 0; kt < 2; kt++)
                    qf[pass * 2 + nn][kt] = *(const v8bf*)(Sw + (nn * 16 + l15) * 128 +
                                                           (((kt * 4 + quad) ^ (l15 & 7)) << 4));
        }
    }

    __syncthreads();   // K, V complete; Sw becomes P^T scratch

    // ---------------- Phase B: flash attention (no-max softmax) ----------------
    v4f O[4][4];
#pragma unroll
    for (int a = 0; a < 4; a++)
#pragma unroll
        for (int b = 0; b < 4; b++) O[a][b] = (v4f){0.f, 0.f, 0.f, 0.f};
    float lsum[4] = {0.f, 0.f, 0.f, 0.f};

    v8bf kf[2][2];
#pragma unroll
    for (int mtk = 0; mtk < 2; mtk++)
#pragma unroll
        for (int kt = 0; kt < 2; kt++) {
            int key = mtk * 16 + l15;
            kf[mtk][kt] = *(const v8bf*)(Kb + key * 128 + (((kt * 4 + quad) ^ (key & 7)) << 4));
        }

#pragma unroll
    for (int t = 0; t < 16; t++) {
        // S^T = K @ Q^T (log2 domain; scale folded into Q)
        v4f s[2][4];
#pragma unroll
        for (int mtk = 0; mtk < 2; mtk++)
#pragma unroll
            for (int nt = 0; nt < 4; nt++) {
                v4f acc = {0.f, 0.f, 0.f, 0.f};
                acc = __builtin_amdgcn_mfma_f32_16x16x32_bf16(kf[mtk][0], qf[nt][0], acc, 0, 0, 0);
                acc = __builtin_amdgcn_mfma_f32_16x16x32_bf16(kf[mtk][1], qf[nt][1], acc, 0, 0, 0);
                s[mtk][nt] = acc;
            }
        // prefetch next tile's K fragments into the softmax window
        int t2 = (t + 1) & 15;
        v8bf kn[2][2];
#pragma unroll
        for (int mtk = 0; mtk < 2; mtk++)
#pragma unroll
            for (int kt = 0; kt < 2; kt++) {
                int key = t2 * 32 + mtk * 16 + l15;
                kn[mtk][kt] = *(const v8bf*)(Kb + key * 128 + (((kt * 4 + quad) ^ (key & 7)) << 4));
            }
        // exp2 (no max subtraction — scores are O(1)), partial l per lane, store P^T
#pragma unroll
        for (int mtk = 0; mtk < 2; mtk++)
#pragma unroll
            for (int nt = 0; nt < 4; nt++) {
                float p0 = __builtin_amdgcn_exp2f(s[mtk][nt][0]);
                float p1 = __builtin_amdgcn_exp2f(s[mtk][nt][1]);
                float p2 = __builtin_amdgcn_exp2f(s[mtk][nt][2]);
                float p3 = __builtin_amdgcn_exp2f(s[mtk][nt][3]);
                lsum[nt] += (p0 + p1) + (p2 + p3);
                v4bf pw;
                pw[0] = (bf16)p0; pw[1] = (bf16)p1; pw[2] = (bf16)p2; pw[3] = (bf16)p3;
                int q = nt * 16 + l15;
                *(v4bf*)(Sw + q * 64 +
                         ((((mtk * 2 + (quad >> 1)) ^ (q & 3)) << 4) | ((quad & 1) << 3))) = pw;
            }
        // V^T fragments (fill the P write->read latency window)
        v8bf vf[4];
#pragma unroll
        for (int mtd = 0; mtd < 4; mtd++) {
            int d = mtd * 16 + l15;
            vf[mtd] = *(const v8bf*)(Vt + d * 1024 + (((t * 4 + quad) ^ (d & 7)) << 4));
        }
        // P^T B-fragments
        v8bf pf[4];
#pragma unroll
        for (int nt = 0; nt < 4; nt++) {
            int q = nt * 16 + l15;
            pf[nt] = *(const v8bf*)(Sw + q * 64 + ((quad ^ (q & 3)) << 4));
        }
        // O^T += V^T @ P^T — pure MFMA chain
#pragma unroll
        for (int mtd = 0; mtd < 4; mtd++)
#pragma unroll
            for (int nt = 0; nt < 4; nt++)
                O[mtd][nt] = __builtin_amdgcn_mfma_f32_16x16x32_bf16(vf[mtd], pf[nt], O[mtd][nt], 0, 0, 0);
        // rotate prefetched K
#pragma unroll
        for (int mtk = 0; mtk < 2; mtk++)
#pragma unroll
            for (int kt = 0; kt < 2; kt++) kf[mtk][kt] = kn[mtk][kt];
    }

    // ---------------- epilogue: out[q] = (sum_d O^T[d][q]) / l[q] ----------------
#pragma unroll
    for (int nt = 0; nt < 4; nt++) {
        float lv = lsum[nt];
        lv += __shfl_xor(lv, 16);
        lv += __shfl_xor(lv, 32);
        float sm = 0.f;
#pragma unroll
        for (int mtd = 0; mtd < 4; mtd++)
#pragma unroll
            for (int r = 0; r < 4; r++) sm += O[mtd][nt][r];
        sm += __shfl_xor(sm, 16);
        sm += __shfl_xor(sm, 32);
        if (quad == 0) out[rowbase + nt * 16 + l15] = sm / lv;
    }
}

extern "C" void kernel_launch(void* const* d_in, const int* in_sizes, int n_in,
                              void* d_out, int out_size, void* d_ws, size_t ws_size,
                              hipStream_t stream) {
    const float* power = (const float*)d_in[0];
    const int*   ele_i = (const int*)d_in[1];
    // d_in[2] = range_indices: unused by the reference (positional reshape)
    const int*   azi_i = (const int*)d_in[3];
    const float* ele_t = (const float*)d_in[4];
    const float* azi_t = (const float*)d_in[5];
    const float* Wq = (const float*)d_in[6];
    const float* bq = (const float*)d_in[7];
    const float* Wk = (const float*)d_in[8];
    const float* bk = (const float*)d_in[9];
    const float* Wv = (const float*)d_in[10];
    const float* bv = (const float*)d_in[11];
    float* out = (float*)d_out;

    (void)hipFuncSetAttribute(reinterpret_cast<const void*>(sda_kernel),
                              hipFuncAttributeMaxDynamicSharedMemorySize, 163840);
    sda_kernel<<<256, 512, 163840, stream>>>(power, ele_i, azi_i, ele_t, azi_t,
                                             Wq, bq, Wk, bk, Wv, bv, out);
}

// Round 3
// 130.066 us; speedup vs baseline: 1.4473x; 1.4473x over previous
//
#include <hip/hip_runtime.h>

// SparseDopplerAttention on gfx950 — R3.
// Key identity: out[q] = (sum_k P[q,k]*vsum[k]) / (sum_k P[q,k]),
//   vsum[k] = x[k] . (sum_d Wv[d,:]) + sum_d bv[d]   (fp32, exact)
// so V GEMM, V^T LDS, and the PV GEMM are eliminated entirely.
// 1 block = 1 range, 1024 threads = 16 waves (4/SIMD), LDS ~66 KB (1 block/CU).
// Each wave owns 32 rows: builds K (bf16, swizzled LDS) + Q (regs) + vsum (fp32 LDS),
// then flash-attends its 32 queries against all 512 keys: S^T = K@Q^T, exp2,
// fma with vsum. No-max softmax (scores O(1) in log2 domain — HW-validated R2).

#define SCALE 0.18033688011112042f   // log2(e)/8

typedef __bf16 bf16;
typedef bf16 v4bf __attribute__((ext_vector_type(4)));
typedef bf16 v8bf __attribute__((ext_vector_type(8)));
typedef float v4f __attribute__((ext_vector_type(4)));

__device__ __forceinline__ v8bf pk8(float4 a, float4 b) {
    v8bf r;
    r[0] = (bf16)a.x; r[1] = (bf16)a.y; r[2] = (bf16)a.z; r[3] = (bf16)a.w;
    r[4] = (bf16)b.x; r[5] = (bf16)b.y; r[6] = (bf16)b.z; r[7] = (bf16)b.w;
    return r;
}
__device__ __forceinline__ float d4(float4 a, v4f w) {
    return a.x * w[0] + a.y * w[1] + a.z * w[2] + a.w * w[3];
}

__global__ __launch_bounds__(1024, 4)
void sda_kernel(const float* __restrict__ power,
                const int*   __restrict__ ele_i,
                const int*   __restrict__ azi_i,
                const float* __restrict__ ele_t,
                const float* __restrict__ azi_t,
                const float* __restrict__ Wq, const float* __restrict__ bq,
                const float* __restrict__ Wk, const float* __restrict__ bk,
                const float* __restrict__ Wv, const float* __restrict__ bv,
                float* __restrict__ out)
{
    extern __shared__ char smem[];
    char*  Kb   = smem;                      // 64 KB: K [key][dim] bf16, 128 B rows, blk16 ^= key&7
    float* vsum = (float*)(smem + 65536);    // 512 f32
    float* wvs  = (float*)(smem + 67584);    // 96 f32 col-sums of Wv + [96]=sum(bv)

    const int tid  = threadIdx.x;
    const int wave = tid >> 6;
    const int lane = tid & 63;
    const int l15  = lane & 15;
    const int quad = lane >> 4;
    const int rowbase = blockIdx.x * 512 + wave * 32;   // this wave's 32 rows

    // ---- wvsum: column sums of Wv (96) + bvsum, cooperative ----
    if (tid < 96) {
        float s = 0.f;
#pragma unroll 8
        for (int r = 0; r < 64; r++) s += Wv[r * 96 + tid];
        wvs[tid] = s;
    } else if (tid == 96) {
        float s = 0.f;
#pragma unroll
        for (int d = 0; d < 64; d++) s += bv[d];
        wvs[96] = s;
    }
    __syncthreads();

    // per-lane wvsum slice (feats quad*8.. in each 32-feat group; embeds land at 64+quad*8)
    v4f w0 = *(const v4f*)(wvs + quad * 8);
    v4f w1 = *(const v4f*)(wvs + quad * 8 + 4);
    v4f w2 = *(const v4f*)(wvs + 32 + quad * 8);
    v4f w3 = *(const v4f*)(wvs + 32 + quad * 8 + 4);
    v4f w4 = *(const v4f*)(wvs + 64 + quad * 8);
    v4f w5 = *(const v4f*)(wvs + 64 + quad * 8 + 4);
    const float bvs = wvs[96];

    // ---- x fragments from global (bf16) + fp32 vsum ----
    v8bf xa[2][3];
#pragma unroll
    for (int mt = 0; mt < 2; mt++) {
        int row = rowbase + mt * 16 + l15;
        const float* pr = power + (size_t)row * 64;
        float4 a0 = *(const float4*)(pr + quad * 8);
        float4 a1 = *(const float4*)(pr + quad * 8 + 4);
        float4 a2 = *(const float4*)(pr + 32 + quad * 8);
        float4 a3 = *(const float4*)(pr + 32 + quad * 8 + 4);
        int ie = ele_i[row];
        int ia = azi_i[row];
        const float* tb = (quad < 2) ? (ele_t + ie * 16 + quad * 8)
                                     : (azi_t + ia * 16 + (quad - 2) * 8);
        float4 a4 = *(const float4*)tb;
        float4 a5 = *(const float4*)(tb + 4);
        xa[mt][0] = pk8(a0, a1);
        xa[mt][1] = pk8(a2, a3);
        xa[mt][2] = pk8(a4, a5);
        float d = d4(a0, w0) + d4(a1, w1) + d4(a2, w2) + d4(a3, w3) + d4(a4, w4) + d4(a5, w5);
        d += __shfl_xor(d, 16);
        d += __shfl_xor(d, 32);
        if (quad == 0) vsum[wave * 32 + mt * 16 + l15] = d + bvs;
    }

    // ---- Q^T = Wq @ x^T (operand swap), fold SCALE, transpose via own K region ----
    char* Sw = Kb + wave * 4096;   // this wave's 32 K-rows; used first as Q scratch
#pragma unroll
    for (int mtd = 0; mtd < 4; mtd++) {
        v8bf wq3[3];
#pragma unroll
        for (int kt = 0; kt < 3; kt++) {
            const float* p = Wq + (mtd * 16 + l15) * 96 + kt * 32 + quad * 8;
            wq3[kt] = pk8(*(const float4*)p, *(const float4*)(p + 4));
        }
        float4 bq4 = *(const float4*)(bq + mtd * 16 + quad * 4);
#pragma unroll
        for (int ntr = 0; ntr < 2; ntr++) {
            v4f acc = {0.f, 0.f, 0.f, 0.f};
#pragma unroll
            for (int kt = 0; kt < 3; kt++)
                acc = __builtin_amdgcn_mfma_f32_16x16x32_bf16(wq3[kt], xa[ntr][kt], acc, 0, 0, 0);
            int row = ntr * 16 + l15;   // local query
            v4bf o;
            o[0] = (bf16)((acc[0] + bq4.x) * SCALE);
            o[1] = (bf16)((acc[1] + bq4.y) * SCALE);
            o[2] = (bf16)((acc[2] + bq4.z) * SCALE);
            o[3] = (bf16)((acc[3] + bq4.w) * SCALE);
            *(v4bf*)(Sw + row * 128 +
                     ((((mtd * 2 + (quad >> 1)) ^ (row & 7)) << 4) | ((quad & 1) << 3))) = o;
        }
    }
    v8bf qf[2][2];
#pragma unroll
    for (int nt = 0; nt < 2; nt++)
#pragma unroll
        for (int kt = 0; kt < 2; kt++)
            qf[nt][kt] = *(const v8bf*)(Sw + (nt * 16 + l15) * 128 +
                                        (((kt * 4 + quad) ^ (l15 & 7)) << 4));

    // ---- K^T = Wk @ x^T, write over the scratch (same-wave DS ops are in-order) ----
#pragma unroll
    for (int mtd = 0; mtd < 4; mtd++) {
        v8bf wk3[3];
#pragma unroll
        for (int kt = 0; kt < 3; kt++) {
            const float* p = Wk + (mtd * 16 + l15) * 96 + kt * 32 + quad * 8;
            wk3[kt] = pk8(*(const float4*)p, *(const float4*)(p + 4));
        }
        float4 bk4 = *(const float4*)(bk + mtd * 16 + quad * 4);
#pragma unroll
        for (int ntr = 0; ntr < 2; ntr++) {
            v4f acc = {0.f, 0.f, 0.f, 0.f};
#pragma unroll
            for (int kt = 0; kt < 3; kt++)
                acc = __builtin_amdgcn_mfma_f32_16x16x32_bf16(wk3[kt], xa[ntr][kt], acc, 0, 0, 0);
            int keyb = wave * 32 + ntr * 16 + l15;
            v4bf o;
            o[0] = (bf16)(acc[0] + bk4.x);
            o[1] = (bf16)(acc[1] + bk4.y);
            o[2] = (bf16)(acc[2] + bk4.z);
            o[3] = (bf16)(acc[3] + bk4.w);
            *(v4bf*)(Kb + keyb * 128 +
                     ((((mtd * 2 + (quad >> 1)) ^ (keyb & 7)) << 4) | ((quad & 1) << 3))) = o;
        }
    }
    __syncthreads();

    // ---- Phase B: S^T = K @ Q^T, exp2, weighted accumulate with vsum ----
    float osum[2] = {0.f, 0.f};
    float lsum[2] = {0.f, 0.f};
#pragma unroll 2
    for (int t = 0; t < 16; t++) {
        v8bf kf[2][2];
#pragma unroll
        for (int mtk = 0; mtk < 2; mtk++)
#pragma unroll
            for (int kt = 0; kt < 2; kt++) {
                int key = t * 32 + mtk * 16 + l15;
                kf[mtk][kt] = *(const v8bf*)(Kb + key * 128 + (((kt * 4 + quad) ^ (key & 7)) << 4));
            }
        v4f vs[2];
#pragma unroll
        for (int mtk = 0; mtk < 2; mtk++)
            vs[mtk] = *(const v4f*)(vsum + t * 32 + mtk * 16 + quad * 4);
#pragma unroll
        for (int mtk = 0; mtk < 2; mtk++) {
#pragma unroll
            for (int nt = 0; nt < 2; nt++) {
                v4f acc = {0.f, 0.f, 0.f, 0.f};
                acc = __builtin_amdgcn_mfma_f32_16x16x32_bf16(kf[mtk][0], qf[nt][0], acc, 0, 0, 0);
                acc = __builtin_amdgcn_mfma_f32_16x16x32_bf16(kf[mtk][1], qf[nt][1], acc, 0, 0, 0);
                float p0 = __builtin_amdgcn_exp2f(acc[0]);
                float p1 = __builtin_amdgcn_exp2f(acc[1]);
                float p2 = __builtin_amdgcn_exp2f(acc[2]);
                float p3 = __builtin_amdgcn_exp2f(acc[3]);
                lsum[nt] += (p0 + p1) + (p2 + p3);
                osum[nt] += ((p0 * vs[mtk][0] + p1 * vs[mtk][1]) +
                             (p2 * vs[mtk][2] + p3 * vs[mtk][3]));
            }
        }
    }

    // ---- epilogue: reduce over key-quads, out = osum/lsum ----
#pragma unroll
    for (int nt = 0; nt < 2; nt++) {
        float lv = lsum[nt];
        lv += __shfl_xor(lv, 16);
        lv += __shfl_xor(lv, 32);
        float ov = osum[nt];
        ov += __shfl_xor(ov, 16);
        ov += __shfl_xor(ov, 32);
        if (quad == 0) out[rowbase + nt * 16 + l15] = ov / lv;
    }
}

extern "C" void kernel_launch(void* const* d_in, const int* in_sizes, int n_in,
                              void* d_out, int out_size, void* d_ws, size_t ws_size,
                              hipStream_t stream) {
    const float* power = (const float*)d_in[0];
    const int*   ele_i = (const int*)d_in[1];
    // d_in[2] = range_indices: unused by the reference (positional reshape)
    const int*   azi_i = (const int*)d_in[3];
    const float* ele_t = (const float*)d_in[4];
    const float* azi_t = (const float*)d_in[5];
    const float* Wq = (const float*)d_in[6];
    const float* bq = (const float*)d_in[7];
    const float* Wk = (const float*)d_in[8];
    const float* bk = (const float*)d_in[9];
    const float* Wv = (const float*)d_in[10];
    const float* bv = (const float*)d_in[11];
    float* out = (float*)d_out;

    const int lds_bytes = 65536 + 2048 + 512;   // Kb + vsum + wvs(97, padded)
    (void)hipFuncSetAttribute(reinterpret_cast<const void*>(sda_kernel),
                              hipFuncAttributeMaxDynamicSharedMemorySize, lds_bytes);
    sda_kernel<<<256, 1024, lds_bytes, stream>>>(power, ele_i, azi_i, ele_t, azi_t,
                                                 Wq, bq, Wk, bk, Wv, bv, out);
}